// Round 2
// baseline (70591.553 us; speedup 1.0000x reference)
//
#include <hip/hip_runtime.h>
#include <hip/hip_fp16.h>

#define T_STEPS 2048
#define BATCH   32
#define DIM     1024
#define NSLICE  8
#define SLICE_COLS 128   // DIM / NSLICE

typedef _Float16 half2_t __attribute__((ext_vector_type(2)));
typedef _Float16 f16x8  __attribute__((ext_vector_type(8)));
typedef float    f32x4  __attribute__((ext_vector_type(4)));

__device__ __forceinline__ float fdot2(unsigned a, unsigned b, float c) {
#if defined(__has_builtin) && __has_builtin(__builtin_amdgcn_fdot2)
    return __builtin_amdgcn_fdot2(__builtin_bit_cast(half2_t, a),
                                  __builtin_bit_cast(half2_t, b), c, false);
#else
    float d;
    asm("v_dot2_f32_f16 %0, %1, %2, %3" : "=v"(d) : "v"(a), "v"(b), "v"(c));
    return d;
#endif
}

// ---------------------------------------------------------------------------
// Kernel 0: zero the cross-wg flags (must be re-zeroed every launch; harness
// does not re-poison d_ws between graph replays).
// ---------------------------------------------------------------------------
__global__ void flag_init(int* __restrict__ flags) {
    flags[threadIdx.x] = 0;
}

// ---------------------------------------------------------------------------
// Kernel 1: repack W_h (fp32 [k][n]) -> f16 pairs, layout P[n][m] where
// m = k>>1 packs (W[2m][n], W[2m+1][n]) into one dword. Thread (col,ks) of the
// rec kernel then loads 16 consecutive uint4 at P + col*512 + ks*64.
// Reads coalesced (lanes span n); writes scattered (one-time 2 MB, cheap).
// ---------------------------------------------------------------------------
__global__ void conv_pack(const float* __restrict__ Wh, unsigned* __restrict__ P) {
    const int i = blockIdx.x * blockDim.x + threadIdx.x;   // 0 .. DIM*DIM/2-1
    const int n = i & (DIM - 1);
    const int m = i >> 10;                                  // pair index 0..511
    half2_t p;
    p[0] = (_Float16)Wh[(size_t)(2 * m)     * DIM + n];
    p[1] = (_Float16)Wh[(size_t)(2 * m + 1) * DIM + n];
    P[(size_t)n * (DIM / 2) + m] = __builtin_bit_cast(unsigned, p);
}

// ---------------------------------------------------------------------------
// Kernel 2: xW = x @ W_x + b  (MFMA 16x16x32, 128x128 tile) -> h_all[1:]
// ---------------------------------------------------------------------------
#define BM 128
#define BN 128
#define BK 32
#define LDT 40

__global__ __launch_bounds__(256) void gemm_xw(
    const float* __restrict__ X,
    const float* __restrict__ Wx,
    const float* __restrict__ bias,
    float* __restrict__ out)
{
    __shared__ _Float16 As[BM][LDT];
    __shared__ _Float16 Bs[BN][LDT];

    const int tid  = threadIdx.x;
    const int m0   = blockIdx.x * BM;
    const int n0   = blockIdx.y * BN;
    const int lane = tid & 63;
    const int wid  = tid >> 6;
    const int wm   = (wid >> 1) * 64;
    const int wn   = (wid & 1) * 64;
    const int lr   = lane & 15;
    const int lk   = (lane >> 4) * 8;

    const int ar = tid >> 1,  ac = (tid & 1) * 16;
    const int bk = tid >> 3,  bn = (tid & 7) * 16;

    f32x4 acc[4][4] = {};

    for (int k0 = 0; k0 < DIM; k0 += BK) {
        __syncthreads();
        {
            const float* src = X + (size_t)(m0 + ar) * DIM + k0 + ac;
            float4 q0 = *(const float4*)(src + 0);
            float4 q1 = *(const float4*)(src + 4);
            float4 q2 = *(const float4*)(src + 8);
            float4 q3 = *(const float4*)(src + 12);
            f16x8 p0, p1;
            p0[0] = (_Float16)q0.x; p0[1] = (_Float16)q0.y;
            p0[2] = (_Float16)q0.z; p0[3] = (_Float16)q0.w;
            p0[4] = (_Float16)q1.x; p0[5] = (_Float16)q1.y;
            p0[6] = (_Float16)q1.z; p0[7] = (_Float16)q1.w;
            p1[0] = (_Float16)q2.x; p1[1] = (_Float16)q2.y;
            p1[2] = (_Float16)q2.z; p1[3] = (_Float16)q2.w;
            p1[4] = (_Float16)q3.x; p1[5] = (_Float16)q3.y;
            p1[6] = (_Float16)q3.z; p1[7] = (_Float16)q3.w;
            *(f16x8*)&As[ar][ac]     = p0;
            *(f16x8*)&As[ar][ac + 8] = p1;
        }
        {
            const float* src = Wx + (size_t)(k0 + bk) * DIM + n0 + bn;
            float4 q0 = *(const float4*)(src + 0);
            float4 q1 = *(const float4*)(src + 4);
            float4 q2 = *(const float4*)(src + 8);
            float4 q3 = *(const float4*)(src + 12);
            float vv[16];
            *(float4*)&vv[0]  = q0; *(float4*)&vv[4]  = q1;
            *(float4*)&vv[8]  = q2; *(float4*)&vv[12] = q3;
            #pragma unroll
            for (int i = 0; i < 16; ++i) Bs[bn + i][bk] = (_Float16)vv[i];
        }
        __syncthreads();
        f16x8 a[4], bb[4];
        #pragma unroll
        for (int f = 0; f < 4; ++f) a[f]  = *(const f16x8*)&As[wm + f * 16 + lr][lk];
        #pragma unroll
        for (int f = 0; f < 4; ++f) bb[f] = *(const f16x8*)&Bs[wn + f * 16 + lr][lk];
        #pragma unroll
        for (int i = 0; i < 4; ++i)
            #pragma unroll
            for (int j = 0; j < 4; ++j)
                acc[i][j] = __builtin_amdgcn_mfma_f32_16x16x32_f16(
                    a[i], bb[j], acc[i][j], 0, 0, 0);
    }

    #pragma unroll
    for (int i = 0; i < 4; ++i) {
        #pragma unroll
        for (int j = 0; j < 4; ++j) {
            const int col = n0 + wn + j * 16 + lr;
            const float bv = bias[col];
            #pragma unroll
            for (int r = 0; r < 4; ++r) {
                const int row = m0 + wm + i * 16 + (lane >> 4) * 4 + r;
                __builtin_nontemporal_store(acc[i][j][r] + bv,
                                            out + (size_t)row * DIM + col);
            }
        }
    }
}

// ---------------------------------------------------------------------------
// Kernel 3: recurrence. 256 wgs = (32 rows x 8 column-slices), one per CU.
// W_h slice (1024 x 128 f16 = 256 KB/CU) register-resident: 64 VGPRs/thread.
// Thread (col_l, ks): col = s*128+col_l, covers k in [ks*128, ks*128+128).
// Exchange medium for h is the h_all[t+1] slot itself (agent-scope atomics +
// per-(row,slice) monotonic flags). LDS h is f16, chunk-skewed to kill bank
// conflicts on the broadcast ds_read_b128.
// ---------------------------------------------------------------------------
__global__ __launch_bounds__(1024) void elman_rec(
    const float* __restrict__ h0,
    const unsigned* __restrict__ P,   // packed W_h
    float* __restrict__ hs,           // [T][B][D]
    float* __restrict__ h_all,        // [T+1][B][D]; [1:] pre-filled with xW
    int* __restrict__ flags)          // [BATCH][NSLICE]
{
    // swizzle so the 8 slices of a row land on one XCD (perf only):
    // XCD ~ blockIdx.x % 8; b = blk & 31 keeps b%8 constant across s.
    const int blk = blockIdx.x;
    const int b   = blk & 31;
    const int s   = blk >> 5;

    const int tid   = threadIdx.x;
    const int col_l = tid >> 3;               // 0..127
    const int ks    = tid & 7;                // k-chunk
    const int col   = s * SLICE_COLS + col_l;

    // skewed f16 h buffer: chunk c at byte c*288, 256B payload + 32B skew
    __shared__ alignas(16) _Float16 hbuf[8 * 144];

    // ---- load W slice into registers (one-time, L3-resident after first CU)
    uint4 wv[16];
    {
        const uint4* wp = (const uint4*)P + (size_t)col * (DIM / 8) + ks * 16;
        #pragma unroll
        for (int r = 0; r < 16; ++r) wv[r] = wp[r];
    }

    // ---- init h0
    {
        const float h0v = h0[(size_t)b * DIM + tid];
        h_all[(size_t)b * DIM + tid] = h0v;
        hbuf[(tid >> 7) * 144 + (tid & 127)] = (_Float16)h0v;
    }
    __syncthreads();

    for (int t = 0; t < T_STEPS; ++t) {
        float* slot = h_all + ((size_t)(t + 1) * BATCH + b) * DIM;

        // xW for my column (issued early, consumed after the reduce)
        const float xw = slot[col];

        // ---- dot over my k-chunk, W in registers, h broadcast from LDS
        float z = 0.0f;
        const char* hb = (const char*)hbuf + ks * 288;
        #pragma unroll
        for (int r = 0; r < 16; ++r) {
            const uint4 hh = *(const uint4*)(hb + r * 16);
            z = fdot2(hh.x, wv[r].x, z);
            z = fdot2(hh.y, wv[r].y, z);
            z = fdot2(hh.z, wv[r].z, z);
            z = fdot2(hh.w, wv[r].w, z);
        }
        // reduce over the 8 k-chunks (lanes differing in low 3 bits)
        z += __shfl_xor(z, 1);
        z += __shfl_xor(z, 2);
        z += __shfl_xor(z, 4);

        if (ks == 0) {
            const float zz = z + xw;
            const float e  = __expf(2.0f * zz);
            const float hn = 1.0f - 2.0f / (e + 1.0f);
            // write-through to the coherent point (no dirty-L2 handoff)
            __hip_atomic_store(slot + col, hn, __ATOMIC_RELAXED,
                               __HIP_MEMORY_SCOPE_AGENT);
        }
        // drain every wave's stores (syncthreads waits vmcnt(0) per wave)
        __syncthreads();
        if (tid == 0)
            __hip_atomic_store(flags + b * NSLICE + s, t + 1, __ATOMIC_RELEASE,
                               __HIP_MEMORY_SCOPE_AGENT);

        // ---- wait for the other 7 slices of this row
        #pragma unroll
        for (int s2 = 0; s2 < NSLICE; ++s2) {
            if (s2 == s) continue;
            const int* fp = flags + b * NSLICE + s2;
            int guard = 0;
            while (__hip_atomic_load(fp, __ATOMIC_RELAXED,
                                     __HIP_MEMORY_SCOPE_AGENT) < t + 1) {
                __builtin_amdgcn_s_sleep(1);
                if (++guard > (1 << 22)) break;   // fail loud, not hung
            }
        }
        __builtin_amdgcn_fence(__ATOMIC_ACQUIRE, "agent");

        // ---- restage full h row (f32 from L3), emit hs[t] coalesced
        const float v = slot[tid];
        hbuf[(tid >> 7) * 144 + (tid & 127)] = (_Float16)v;
        __builtin_nontemporal_store(v, hs + ((size_t)t * BATCH + b) * DIM + tid);
        __syncthreads();
    }
}

extern "C" void kernel_launch(void* const* d_in, const int* in_sizes, int n_in,
                              void* d_out, int out_size, void* d_ws, size_t ws_size,
                              hipStream_t stream) {
    const float* x    = (const float*)d_in[0];   // [T][B][D]
    const float* h0   = (const float*)d_in[1];   // [B][D]
    const float* Wx   = (const float*)d_in[2];   // [D][D]
    const float* Wh   = (const float*)d_in[3];   // [D][D]
    const float* bias = (const float*)d_in[4];   // [D]

    float* hs    = (float*)d_out;
    float* h_all = hs + (size_t)T_STEPS * BATCH * DIM;

    int*      flags = (int*)d_ws;                               // 1 KB
    unsigned* P     = (unsigned*)((char*)d_ws + 4096);          // 2 MB packed W_h

    flag_init<<<1, BATCH * NSLICE, 0, stream>>>(flags);

    conv_pack<<<(DIM * DIM / 2) / 256, 256, 0, stream>>>(Wh, P);

    dim3 g((T_STEPS * BATCH) / BM, DIM / BN);
    gemm_xw<<<g, 256, 0, stream>>>(x, Wx, bias, h_all + (size_t)BATCH * DIM);

    elman_rec<<<BATCH * NSLICE, 1024, 0, stream>>>(h0, P, hs, h_all, flags);
}

// Round 3
// 66074.896 us; speedup vs baseline: 1.0684x; 1.0684x over previous
//
#include <hip/hip_runtime.h>
#include <hip/hip_fp16.h>

#define T_STEPS 2048
#define BATCH   32
#define DIM     1024
#define NSLICE  8
#define SLICE_COLS 128   // DIM / NSLICE

typedef _Float16 half2_t __attribute__((ext_vector_type(2)));
typedef _Float16 f16x8  __attribute__((ext_vector_type(8)));
typedef float    f32x4  __attribute__((ext_vector_type(4)));

__device__ __forceinline__ float fdot2(unsigned a, unsigned b, float c) {
#if defined(__has_builtin) && __has_builtin(__builtin_amdgcn_fdot2)
    return __builtin_amdgcn_fdot2(__builtin_bit_cast(half2_t, a),
                                  __builtin_bit_cast(half2_t, b), c, false);
#else
    float d;
    asm("v_dot2_f32_f16 %0, %1, %2, %3" : "=v"(d) : "v"(a), "v"(b), "v"(c));
    return d;
#endif
}

// ---------------------------------------------------------------------------
// Kernel 0: zero cross-wg flags (d_ws is not re-poisoned between replays).
// ---------------------------------------------------------------------------
__global__ void flag_init(int* __restrict__ flags) {
    flags[threadIdx.x] = 0;
}

// ---------------------------------------------------------------------------
// Kernel 1: repack W_h (fp32 [k][n]) -> f16 pairs P[n][m], m=k>>1 packing
// (W[2m][n], W[2m+1][n]) into one dword.
// ---------------------------------------------------------------------------
__global__ void conv_pack(const float* __restrict__ Wh, unsigned* __restrict__ P) {
    const int i = blockIdx.x * blockDim.x + threadIdx.x;   // 0 .. DIM*DIM/2-1
    const int n = i & (DIM - 1);
    const int m = i >> 10;                                  // pair index 0..511
    half2_t p;
    p[0] = (_Float16)Wh[(size_t)(2 * m)     * DIM + n];
    p[1] = (_Float16)Wh[(size_t)(2 * m + 1) * DIM + n];
    P[(size_t)n * (DIM / 2) + m] = __builtin_bit_cast(unsigned, p);
}

// ---------------------------------------------------------------------------
// Kernel 2: xW = x @ W_x + b  (MFMA 16x16x32, 128x128 tile) -> h_all[1:]
// ---------------------------------------------------------------------------
#define BM 128
#define BN 128
#define BK 32
#define LDT 40

__global__ __launch_bounds__(256) void gemm_xw(
    const float* __restrict__ X,
    const float* __restrict__ Wx,
    const float* __restrict__ bias,
    float* __restrict__ out)
{
    __shared__ _Float16 As[BM][LDT];
    __shared__ _Float16 Bs[BN][LDT];

    const int tid  = threadIdx.x;
    const int m0   = blockIdx.x * BM;
    const int n0   = blockIdx.y * BN;
    const int lane = tid & 63;
    const int wid  = tid >> 6;
    const int wm   = (wid >> 1) * 64;
    const int wn   = (wid & 1) * 64;
    const int lr   = lane & 15;
    const int lk   = (lane >> 4) * 8;

    const int ar = tid >> 1,  ac = (tid & 1) * 16;
    const int bk = tid >> 3,  bn = (tid & 7) * 16;

    f32x4 acc[4][4] = {};

    for (int k0 = 0; k0 < DIM; k0 += BK) {
        __syncthreads();
        {
            const float* src = X + (size_t)(m0 + ar) * DIM + k0 + ac;
            float4 q0 = *(const float4*)(src + 0);
            float4 q1 = *(const float4*)(src + 4);
            float4 q2 = *(const float4*)(src + 8);
            float4 q3 = *(const float4*)(src + 12);
            f16x8 p0, p1;
            p0[0] = (_Float16)q0.x; p0[1] = (_Float16)q0.y;
            p0[2] = (_Float16)q0.z; p0[3] = (_Float16)q0.w;
            p0[4] = (_Float16)q1.x; p0[5] = (_Float16)q1.y;
            p0[6] = (_Float16)q1.z; p0[7] = (_Float16)q1.w;
            p1[0] = (_Float16)q2.x; p1[1] = (_Float16)q2.y;
            p1[2] = (_Float16)q2.z; p1[3] = (_Float16)q2.w;
            p1[4] = (_Float16)q3.x; p1[5] = (_Float16)q3.y;
            p1[6] = (_Float16)q3.z; p1[7] = (_Float16)q3.w;
            *(f16x8*)&As[ar][ac]     = p0;
            *(f16x8*)&As[ar][ac + 8] = p1;
        }
        {
            const float* src = Wx + (size_t)(k0 + bk) * DIM + n0 + bn;
            float4 q0 = *(const float4*)(src + 0);
            float4 q1 = *(const float4*)(src + 4);
            float4 q2 = *(const float4*)(src + 8);
            float4 q3 = *(const float4*)(src + 12);
            float vv[16];
            *(float4*)&vv[0]  = q0; *(float4*)&vv[4]  = q1;
            *(float4*)&vv[8]  = q2; *(float4*)&vv[12] = q3;
            #pragma unroll
            for (int i = 0; i < 16; ++i) Bs[bn + i][bk] = (_Float16)vv[i];
        }
        __syncthreads();
        f16x8 a[4], bb[4];
        #pragma unroll
        for (int f = 0; f < 4; ++f) a[f]  = *(const f16x8*)&As[wm + f * 16 + lr][lk];
        #pragma unroll
        for (int f = 0; f < 4; ++f) bb[f] = *(const f16x8*)&Bs[wn + f * 16 + lr][lk];
        #pragma unroll
        for (int i = 0; i < 4; ++i)
            #pragma unroll
            for (int j = 0; j < 4; ++j)
                acc[i][j] = __builtin_amdgcn_mfma_f32_16x16x32_f16(
                    a[i], bb[j], acc[i][j], 0, 0, 0);
    }

    #pragma unroll
    for (int i = 0; i < 4; ++i) {
        #pragma unroll
        for (int j = 0; j < 4; ++j) {
            const int col = n0 + wn + j * 16 + lr;
            const float bv = bias[col];
            #pragma unroll
            for (int r = 0; r < 4; ++r) {
                const int row = m0 + wm + i * 16 + (lane >> 4) * 4 + r;
                __builtin_nontemporal_store(acc[i][j][r] + bv,
                                            out + (size_t)row * DIM + col);
            }
        }
    }
}

// ---------------------------------------------------------------------------
// Kernel 3: recurrence. 256 wgs = (32 rows x 8 column-slices), 1 per CU
// (enforced by __launch_bounds__(1024,4): 4 waves/SIMD -> 128-VGPR budget so
// the 64-VGPR W slice stays register-resident -- round-2 spilled at the
// default 8-waves/SIMD target).
// Exchange medium: the h_all[t+1] slot itself, agent-scope write-through +
// per-(row,slice) monotonic flags; 8 slices of a row share an XCD by layout.
// ---------------------------------------------------------------------------
__global__ __launch_bounds__(1024, 4) void elman_rec(
    const float* __restrict__ h0,
    const unsigned* __restrict__ P,   // packed W_h
    float* __restrict__ hs,           // [T][B][D]
    float* __restrict__ h_all,        // [T+1][B][D]; [1:] pre-filled with xW
    int* __restrict__ flags)          // [BATCH][NSLICE]
{
    const int blk = blockIdx.x;
    const int b   = blk & 31;         // row; b%8 == XCD for all 8 slices
    const int s   = blk >> 5;         // column-slice

    const int tid   = threadIdx.x;
    const int col_l = tid >> 3;               // 0..127
    const int ks    = tid & 7;                // k-chunk
    const int col   = s * SLICE_COLS + col_l;

    // skewed f16 h buffer: chunk c at byte c*272 (256B payload + 16B skew)
    // 272/4 = 68 ≡ 4 (mod 32): the 8 chunk bases hit 8 distinct bank quads.
    __shared__ alignas(16) _Float16 hbuf[8 * 136];

    // ---- W slice -> registers (64 VGPRs/thread; 256 KB/CU)
    uint4 wv[16];
    {
        const uint4* wp = (const uint4*)P + (size_t)col * (DIM / 8) + ks * 16;
        #pragma unroll
        for (int r = 0; r < 16; ++r) wv[r] = wp[r];
    }

    // ---- init h0
    {
        const float h0v = h0[(size_t)b * DIM + tid];
        h_all[(size_t)b * DIM + tid] = h0v;
        hbuf[(tid >> 7) * 136 + (tid & 127)] = (_Float16)h0v;
    }
    __syncthreads();

    for (int t = 0; t < T_STEPS; ++t) {
        float* slot = h_all + ((size_t)(t + 1) * BATCH + b) * DIM;

        // xW for my column (own slice only; overwritten below by own wg)
        const float xw = slot[col];

        // ---- dot over my k-chunk: W in registers, h broadcast from LDS
        float z = 0.0f;
        const char* hb = (const char*)hbuf + ks * 272;
        #pragma unroll
        for (int r = 0; r < 16; ++r) {
            const uint4 hh = *(const uint4*)(hb + r * 16);
            z = fdot2(hh.x, wv[r].x, z);
            z = fdot2(hh.y, wv[r].y, z);
            z = fdot2(hh.z, wv[r].z, z);
            z = fdot2(hh.w, wv[r].w, z);
        }
        z += __shfl_xor(z, 1);
        z += __shfl_xor(z, 2);
        z += __shfl_xor(z, 4);

        if (ks == 0) {
            const float zz = z + xw;
            const float e  = __expf(2.0f * zz);
            const float hn = 1.0f - 2.0f / (e + 1.0f);
            __hip_atomic_store(slot + col, hn, __ATOMIC_RELAXED,
                               __HIP_MEMORY_SCOPE_AGENT);
        }
        __syncthreads();   // all waves' stores drained (vmcnt(0) before barrier)
        if (tid == 0)
            __hip_atomic_store(flags + b * NSLICE + s, t + 1, __ATOMIC_RELEASE,
                               __HIP_MEMORY_SCOPE_AGENT);

        // ---- 8 threads wait on the 7 peer slices (not all 1024)
        if (tid < NSLICE && tid != s) {
            const int* fp = flags + b * NSLICE + tid;
            int guard = 0;
            while (__hip_atomic_load(fp, __ATOMIC_RELAXED,
                                     __HIP_MEMORY_SCOPE_AGENT) < t + 1) {
                if (++guard > (1 << 22)) break;   // fail loud, not hung
            }
        }
        __syncthreads();
        __builtin_amdgcn_fence(__ATOMIC_ACQUIRE, "agent");

        // ---- restage full h row from L3; emit hs[t] coalesced
        const float v = slot[tid];
        hbuf[(tid >> 7) * 136 + (tid & 127)] = (_Float16)v;
        __builtin_nontemporal_store(v, hs + ((size_t)t * BATCH + b) * DIM + tid);
        __syncthreads();
    }
}

extern "C" void kernel_launch(void* const* d_in, const int* in_sizes, int n_in,
                              void* d_out, int out_size, void* d_ws, size_t ws_size,
                              hipStream_t stream) {
    const float* x    = (const float*)d_in[0];   // [T][B][D]
    const float* h0   = (const float*)d_in[1];   // [B][D]
    const float* Wx   = (const float*)d_in[2];   // [D][D]
    const float* Wh   = (const float*)d_in[3];   // [D][D]
    const float* bias = (const float*)d_in[4];   // [D]

    float* hs    = (float*)d_out;
    float* h_all = hs + (size_t)T_STEPS * BATCH * DIM;

    int*      flags = (int*)d_ws;                               // 1 KB
    unsigned* P     = (unsigned*)((char*)d_ws + 4096);          // 2 MB packed W_h

    flag_init<<<1, BATCH * NSLICE, 0, stream>>>(flags);

    conv_pack<<<(DIM * DIM / 2) / 256, 256, 0, stream>>>(Wh, P);

    dim3 g((T_STEPS * BATCH) / BM, DIM / BN);
    gemm_xw<<<g, 256, 0, stream>>>(x, Wx, bias, h_all + (size_t)BATCH * DIM);

    elman_rec<<<BATCH * NSLICE, 1024, 0, stream>>>(h0, P, hs, h_all, flags);
}